// Round 1
// baseline (116.331 us; speedup 1.0000x reference)
//
#include <hip/hip_runtime.h>
#include <hip/hip_bf16.h>
#include <math.h>

// Problem: N=65536 rows, C=1000 classes.
// loss = (1/N) * sum_i ( psum_i * lse_i - dot_i )
//   lse_i  = max_k x[i,k] + log(sum_k exp(x[i,k]-max))
//   dot_i  = sum_k P[i,k]*x[i,k]
//   psum_i = sum_k P[i,k]
//
// Kernel 1: one 64-lane wave per row, single pass over memory (registers hold
// the row), shuffle-only reductions. Kernel 2: deterministic final reduce.

#define NROWS 65536
#define NC    1000
#define NC4   250          // 1000 floats = 250 float4 (row stride 4000B, 16B aligned)
#define LOG2E 1.4426950408889634f
#define LN2   0.6931471805599453f

__global__ __launch_bounds__(256) void ebem_row_kernel(
    const float* __restrict__ x, const float* __restrict__ p,
    float* __restrict__ row_out)
{
    const int lane = threadIdx.x & 63;
    const int wave = threadIdx.x >> 6;                 // 0..3
    const long long row = (long long)blockIdx.x * 4 + wave;

    const float4* xr = (const float4*)(x + row * (long long)NC);
    const float4* pr = (const float4*)(p + row * (long long)NC);

    float4 xs[4], ps[4];
    float m = -INFINITY;

    // One coalesced pass: lane l owns chunks l, l+64, l+128, l+192 (<250).
    #pragma unroll
    for (int k = 0; k < 4; ++k) {
        const int idx = lane + 64 * k;
        if (idx < NC4) {
            xs[k] = xr[idx];
            ps[k] = pr[idx];
            m = fmaxf(m, fmaxf(fmaxf(xs[k].x, xs[k].y),
                               fmaxf(xs[k].z, xs[k].w)));
        }
    }

    // Wave-wide max (64 lanes).
    #pragma unroll
    for (int off = 32; off; off >>= 1)
        m = fmaxf(m, __shfl_xor(m, off));

    // exp-sum, P·x, sum(P) from registers (no memory re-read).
    float s = 0.f, dot = 0.f, psum = 0.f;
    #pragma unroll
    for (int k = 0; k < 4; ++k) {
        const int idx = lane + 64 * k;
        if (idx < NC4) {
            s += exp2f((xs[k].x - m) * LOG2E);
            s += exp2f((xs[k].y - m) * LOG2E);
            s += exp2f((xs[k].z - m) * LOG2E);
            s += exp2f((xs[k].w - m) * LOG2E);
            dot  += ps[k].x * xs[k].x + ps[k].y * xs[k].y
                  + ps[k].z * xs[k].z + ps[k].w * xs[k].w;
            psum += ps[k].x + ps[k].y + ps[k].z + ps[k].w;
        }
    }

    #pragma unroll
    for (int off = 32; off; off >>= 1) {
        s    += __shfl_xor(s, off);
        dot  += __shfl_xor(dot, off);
        psum += __shfl_xor(psum, off);
    }

    if (lane == 0) {
        const float lse = m + log2f(s) * LN2;
        row_out[row] = psum * lse - dot;
    }
}

__global__ __launch_bounds__(1024) void ebem_reduce_kernel(
    const float* __restrict__ row_vals, float* __restrict__ out)
{
    const int tid  = threadIdx.x;
    const int lane = tid & 63;
    const int wid  = tid >> 6;

    double acc = 0.0;
    for (int i = tid; i < NROWS; i += 1024)
        acc += (double)row_vals[i];

    #pragma unroll
    for (int off = 32; off; off >>= 1)
        acc += __shfl_xor(acc, off);

    __shared__ double sm[16];
    if (lane == 0) sm[wid] = acc;
    __syncthreads();

    if (tid < 16) {
        acc = sm[tid];
        #pragma unroll
        for (int off = 8; off; off >>= 1)
            acc += __shfl_xor(acc, off);
        if (tid == 0)
            out[0] = (float)(acc / (double)NROWS);
    }
}

extern "C" void kernel_launch(void* const* d_in, const int* in_sizes, int n_in,
                              void* d_out, int out_size, void* d_ws, size_t ws_size,
                              hipStream_t stream) {
    const float* x = (const float*)d_in[0];
    const float* p = (const float*)d_in[1];
    float* row_vals = (float*)d_ws;          // 65536 floats = 256 KiB
    float* out = (float*)d_out;

    ebem_row_kernel<<<NROWS / 4, 256, 0, stream>>>(x, p, row_vals);
    ebem_reduce_kernel<<<1, 1024, 0, stream>>>(row_vals, out);
}

// Round 3
// 87.826 us; speedup vs baseline: 1.3246x; 1.3246x over previous
//
#include <hip/hip_runtime.h>
#include <hip/hip_bf16.h>
#include <math.h>

// Problem: N=65536 rows, C=1000 classes.
// loss = (1/N) * sum_i ( psum_i * lse_i - dot_i )
//   lse_i  = max_k x[i,k] + log(sum_k exp(x[i,k]-max))
//   dot_i  = sum_k P[i,k]*x[i,k]
//   psum_i = sum_k P[i,k]
//
// Kernel 1: one 64-lane wave per row (4 rows/block), single nontemporal pass
// over memory (registers hold the row), shuffle-only reductions, one partial
// sum per BLOCK written to d_ws. Kernel 2: deterministic final reduce.

#define NROWS  65536
#define NC     1000
#define NC4    250          // 1000 floats = 250 float4 (row stride 4000B, 16B aligned)
#define NBLK   (NROWS / 4)  // 16384 partial sums
#define LOG2E  1.4426950408889634f
#define LN2    0.6931471805599453f

typedef float f32x4 __attribute__((ext_vector_type(4)));

__global__ __launch_bounds__(256) void ebem_row_kernel(
    const float* __restrict__ x, const float* __restrict__ p,
    float* __restrict__ blk_out)
{
    const int lane = threadIdx.x & 63;
    const int wave = threadIdx.x >> 6;                 // 0..3
    const long long row = (long long)blockIdx.x * 4 + wave;

    const f32x4* xr = (const f32x4*)(x + row * (long long)NC);
    const f32x4* pr = (const f32x4*)(p + row * (long long)NC);

    f32x4 xs[4], ps[4];
    float m = -INFINITY;

    // One coalesced nontemporal pass. Group the x-stream loads together,
    // then the p-stream loads (4KB sequential burst per stream per wave).
    #pragma unroll
    for (int k = 0; k < 4; ++k) {
        const int idx = lane + 64 * k;
        if (idx < NC4) xs[k] = __builtin_nontemporal_load(&xr[idx]);
    }
    #pragma unroll
    for (int k = 0; k < 4; ++k) {
        const int idx = lane + 64 * k;
        if (idx < NC4) ps[k] = __builtin_nontemporal_load(&pr[idx]);
    }

    #pragma unroll
    for (int k = 0; k < 4; ++k) {
        const int idx = lane + 64 * k;
        if (idx < NC4)
            m = fmaxf(m, fmaxf(fmaxf(xs[k].x, xs[k].y),
                               fmaxf(xs[k].z, xs[k].w)));
    }

    // Wave-wide max (64 lanes).
    #pragma unroll
    for (int off = 32; off; off >>= 1)
        m = fmaxf(m, __shfl_xor(m, off));

    // exp-sum, P·x, sum(P) from registers (no memory re-read).
    float s = 0.f, dot = 0.f, psum = 0.f;
    #pragma unroll
    for (int k = 0; k < 4; ++k) {
        const int idx = lane + 64 * k;
        if (idx < NC4) {
            s += exp2f((xs[k].x - m) * LOG2E);
            s += exp2f((xs[k].y - m) * LOG2E);
            s += exp2f((xs[k].z - m) * LOG2E);
            s += exp2f((xs[k].w - m) * LOG2E);
            dot  += ps[k].x * xs[k].x + ps[k].y * xs[k].y
                  + ps[k].z * xs[k].z + ps[k].w * xs[k].w;
            psum += ps[k].x + ps[k].y + ps[k].z + ps[k].w;
        }
    }

    #pragma unroll
    for (int off = 32; off; off >>= 1) {
        s    += __shfl_xor(s, off);
        dot  += __shfl_xor(dot, off);
        psum += __shfl_xor(psum, off);
    }

    __shared__ float part[4];
    if (lane == 0) {
        const float lse = m + log2f(s) * LN2;
        part[wave] = psum * lse - dot;
    }
    __syncthreads();
    if (threadIdx.x == 0)
        blk_out[blockIdx.x] = (part[0] + part[1]) + (part[2] + part[3]);
}

__global__ __launch_bounds__(1024) void ebem_reduce_kernel(
    const float* __restrict__ blk_vals, float* __restrict__ out)
{
    const int tid  = threadIdx.x;
    const int lane = tid & 63;
    const int wid  = tid >> 6;

    double acc = 0.0;
    #pragma unroll
    for (int i = tid; i < NBLK; i += 1024)
        acc += (double)blk_vals[i];

    #pragma unroll
    for (int off = 32; off; off >>= 1)
        acc += __shfl_xor(acc, off);

    __shared__ double sm[16];
    if (lane == 0) sm[wid] = acc;
    __syncthreads();

    if (tid < 16) {
        acc = sm[tid];
        #pragma unroll
        for (int off = 8; off; off >>= 1)
            acc += __shfl_xor(acc, off);
        if (tid == 0)
            out[0] = (float)(acc / (double)NROWS);
    }
}

extern "C" void kernel_launch(void* const* d_in, const int* in_sizes, int n_in,
                              void* d_out, int out_size, void* d_ws, size_t ws_size,
                              hipStream_t stream) {
    const float* x = (const float*)d_in[0];
    const float* p = (const float*)d_in[1];
    float* blk_vals = (float*)d_ws;          // 16384 floats = 64 KiB
    float* out = (float*)d_out;

    ebem_row_kernel<<<NBLK, 256, 0, stream>>>(x, p, blk_vals);
    ebem_reduce_kernel<<<1, 1024, 0, stream>>>(blk_vals, out);
}